// Round 1
// 398.225 us; speedup vs baseline: 1.0366x; 1.0366x over previous
//
#include <hip/hip_runtime.h>

typedef unsigned short u16;
typedef __attribute__((ext_vector_type(8))) __bf16 bf16x8;
typedef __attribute__((ext_vector_type(4))) float floatx4;

#define DDIM 2048
#define MROWS 16384   // 4*4096

__device__ __forceinline__ u16 f2bf(float f) {
    unsigned int u = __builtin_bit_cast(unsigned int, f);
    u = (u + 0x7fffu + ((u >> 16) & 1u)) >> 16;   // RNE
    return (u16)u;
}

__device__ __forceinline__ float wave_sum(float v) {
#pragma unroll
    for (int o = 32; o > 0; o >>= 1) v += __shfl_down(v, o, 64);
    return v;
}
__device__ __forceinline__ float wave_max(float v) {
#pragma unroll
    for (int o = 32; o > 0; o >>= 1) v = fmaxf(v, __shfl_down(v, o, 64));
    return v;
}

// ---------------- partial sums of |W| ----------------
__global__ __launch_bounds__(256) void absmean_part(const float4* __restrict__ W4,
                                                    float* __restrict__ partial) {
    float s = 0.f;
    for (int i = blockIdx.x * 256 + threadIdx.x; i < (DDIM * DDIM / 4); i += 1024 * 256) {
        float4 v = W4[i];
        s += fabsf(v.x) + fabsf(v.y) + fabsf(v.z) + fabsf(v.w);
    }
    s = wave_sum(s);
    __shared__ float red[4];
    if ((threadIdx.x & 63) == 0) red[threadIdx.x >> 6] = s;
    __syncthreads();
    if (threadIdx.x == 0) partial[blockIdx.x] = red[0] + red[1] + red[2] + red[3];
}

// ---------------- transpose (optionally fused w_scale finalize + ternary quantize) ----
template <bool QUANT>
__global__ __launch_bounds__(256) void transpose_k(const float* __restrict__ in,
                                                   float* __restrict__ out,
                                                   const float* __restrict__ partial) {
    __shared__ float tile[64][65];
    const int t = threadIdx.x;
    float wsc = 0.f, half_t = 0.f;
    if (QUANT) {
        __shared__ float wred[4];
        float s = partial[t] + partial[t + 256] + partial[t + 512] + partial[t + 768];
        s = wave_sum(s);
        if ((t & 63) == 0) wred[t >> 6] = s;
        __syncthreads();
        float m = (wred[0] + wred[1] + wred[2] + wred[3]) * (1.0f / (float)(DDIM * DDIM));
        wsc = fmaxf(m, 1e-6f);
        half_t = 0.5f * wsc;
        __syncthreads();
    }
    const int tx = t & 63;
    const int ty = t >> 6;
    const int r0 = blockIdx.y * 64;
    const int c0 = blockIdx.x * 64;
#pragma unroll
    for (int i = 0; i < 16; ++i) {
        int r = ty + i * 4;
        float w = in[(size_t)(r0 + r) * DDIM + c0 + tx];
        if (QUANT) w = (w > half_t ? wsc : 0.f) + (w < -half_t ? -wsc : 0.f);
        tile[r][tx] = w;
    }
    __syncthreads();
#pragma unroll
    for (int i = 0; i < 16; ++i) {
        int r = ty + i * 4;
        out[(size_t)(c0 + r) * DDIM + r0 + tx] = tile[tx][r];
    }
}

// ---------------- row FWHT (length 2048) -------------------------------------
template <bool BF16OUT>
__global__ __launch_bounds__(256) void fwht_rows(const float* __restrict__ in,
                                                 void* __restrict__ out) {
    __shared__ float s0[DDIM];
    __shared__ float s1[DDIM];
    const int row = blockIdx.x;
    const int t = threadIdx.x;
    const int lane = t & 63;
    const float4* rp = (const float4*)(in + (size_t)row * DDIM);
    float4 a = rp[t], b = rp[t + 256];
    float v[8] = {a.x, a.y, a.z, a.w, b.x, b.y, b.z, b.w};

#pragma unroll
    for (int h = 1; h <= 4; h <<= 1)
#pragma unroll
        for (int j = 0; j < 8; ++j)
            if (!(j & h)) { float x = v[j], y = v[j | h]; v[j] = x + y; v[j | h] = x - y; }

#pragma unroll
    for (int m = 1; m <= 32; m <<= 1)
#pragma unroll
        for (int j = 0; j < 8; ++j) {
            float p = __shfl_xor(v[j], m, 64);
            v[j] = (lane & m) ? (p - v[j]) : (p + v[j]);
        }

    ((float4*)s0)[2 * t] = make_float4(v[0], v[1], v[2], v[3]);
    ((float4*)s0)[2 * t + 1] = make_float4(v[4], v[5], v[6], v[7]);
    __syncthreads();
    {
        int p1 = t ^ 64;
        float4 pa = ((const float4*)s0)[2 * p1], pb = ((const float4*)s0)[2 * p1 + 1];
        float pv[8] = {pa.x, pa.y, pa.z, pa.w, pb.x, pb.y, pb.z, pb.w};
#pragma unroll
        for (int j = 0; j < 8; ++j) v[j] = (t & 64) ? (pv[j] - v[j]) : (pv[j] + v[j]);
    }
    ((float4*)s1)[2 * t] = make_float4(v[0], v[1], v[2], v[3]);
    ((float4*)s1)[2 * t + 1] = make_float4(v[4], v[5], v[6], v[7]);
    __syncthreads();
    {
        int p2 = t ^ 128;
        float4 pa = ((const float4*)s1)[2 * p2], pb = ((const float4*)s1)[2 * p2 + 1];
        float pv[8] = {pa.x, pa.y, pa.z, pa.w, pb.x, pb.y, pb.z, pb.w};
#pragma unroll
        for (int j = 0; j < 8; ++j) v[j] = (t & 128) ? (pv[j] - v[j]) : (pv[j] + v[j]);
    }

    if (BF16OUT) {
        u16* op = (u16*)out + (size_t)row * DDIM;
        uint2 o0, o1;
        o0.x = (unsigned)f2bf(v[0]) | ((unsigned)f2bf(v[1]) << 16);
        o0.y = (unsigned)f2bf(v[2]) | ((unsigned)f2bf(v[3]) << 16);
        o1.x = (unsigned)f2bf(v[4]) | ((unsigned)f2bf(v[5]) << 16);
        o1.y = (unsigned)f2bf(v[6]) | ((unsigned)f2bf(v[7]) << 16);
        ((uint2*)op)[t] = o0;
        ((uint2*)op)[t + 256] = o1;
    } else {
        float* op = (float*)out + (size_t)row * DDIM;
        ((float4*)op)[t] = make_float4(v[0], v[1], v[2], v[3]);
        ((float4*)op)[t + 256] = make_float4(v[4], v[5], v[6], v[7]);
    }
}

// ---------------- fused LayerNorm + int4 fake-quant -> bf16 ----------------
__global__ __launch_bounds__(256) void ln_quant(const float* __restrict__ X,
                                                const float* __restrict__ G,
                                                const float* __restrict__ Bt,
                                                u16* __restrict__ XQ) {
    const int row = blockIdx.x;
    const int t = threadIdx.x;
    const float4* rp = (const float4*)(X + (size_t)row * DDIM);
    float4 v0 = rp[t], v1 = rp[t + 256];
    float v[8] = {v0.x, v0.y, v0.z, v0.w, v1.x, v1.y, v1.z, v1.w};

    __shared__ float redA[4], redB[4], redC[4];
    const int wv = t >> 6, ln = t & 63;

    float s = 0.f, s2 = 0.f;
#pragma unroll
    for (int j = 0; j < 8; ++j) { s += v[j]; s2 += v[j] * v[j]; }
#pragma unroll
    for (int o = 32; o > 0; o >>= 1) {
        s += __shfl_down(s, o, 64);
        s2 += __shfl_down(s2, o, 64);
    }
    if (ln == 0) { redA[wv] = s; redB[wv] = s2; }
    __syncthreads();
    const float mu = (redA[0] + redA[1] + redA[2] + redA[3]) * (1.f / (float)DDIM);
    const float ex2 = (redB[0] + redB[1] + redB[2] + redB[3]) * (1.f / (float)DDIM);
    const float var = ex2 - mu * mu;
    const float rstd = rsqrtf(var + 1e-5f);

    const float4* gp = (const float4*)G;
    const float4* bp = (const float4*)Bt;
    float4 g0 = gp[t], g1 = gp[t + 256];
    float4 b0 = bp[t], b1 = bp[t + 256];
    float gg[8] = {g0.x, g0.y, g0.z, g0.w, g1.x, g1.y, g1.z, g1.w};
    float bb[8] = {b0.x, b0.y, b0.z, b0.w, b1.x, b1.y, b1.z, b1.w};

    float y[8];
    float am = 0.f;
#pragma unroll
    for (int j = 0; j < 8; ++j) {
        y[j] = (v[j] - mu) * rstd * gg[j] + bb[j];
        am = fmaxf(am, fabsf(y[j]));
    }
    float w = wave_max(am);
    if (ln == 0) redC[wv] = w;
    __syncthreads();
    const float scale = fmaxf(fmaxf(fmaxf(redC[0], redC[1]), fmaxf(redC[2], redC[3])), 1e-6f);

    const float r7 = 7.f / scale, s7 = scale / 7.f;
    unsigned int q[4];
#pragma unroll
    for (int j = 0; j < 8; j += 2) {
        float qa = fminf(fmaxf(rintf(y[j] * r7), -7.f), 7.f);
        float qb = fminf(fmaxf(rintf(y[j + 1] * r7), -7.f), 7.f);
        q[j >> 1] = (unsigned)f2bf(qa * s7) | ((unsigned)f2bf(qb * s7) << 16);
    }
    uint2 o0, o1;
    o0.x = q[0]; o0.y = q[1]; o1.x = q[2]; o1.y = q[3];
    uint2* orow = (uint2*)(XQ + (size_t)row * DDIM);
    orow[t] = o0;
    orow[t + 256] = o1;
}

// ---------------- GEMM: 256x256 tile, 8-phase counted-vmcnt pipeline ----------------
// C[16384][2048] = A[16384][2048] * B[2048(N)][2048(K)]^T, bf16 in / f32 out.
// 512 thr = 8 waves (2M x 4N); per-wave 128x64 output as 8x4 16x16x32 frags.
// LDS 128 KiB: 2 bufs x (A 256x64 + B 256x64) bf16. Chunk-swizzle pos^=(row&7),
// pre-swizzled global source (both-sides rule). Per K-tile 4 phases:
//   P1 reads A-half0+B-half0 | P2 reads B-half1 | P3 reads A-half1 + stage B(kt+2)
//   (B slots dead after P2)  | P4 stage A(kt+2) (A slots dead after P3).
// One counted s_waitcnt vmcnt(8) per K-tile (8 loads = next K-tile stay in flight).
#define GBK 64
#define GNT (DDIM / GBK)      // 32
#define TILEU (256 * GBK)     // 16384 u16 per staged tile

__device__ __forceinline__ void gl_lds16(const u16* g, u16* l) {
    __builtin_amdgcn_global_load_lds((const __attribute__((address_space(1))) void*)g,
                                     (__attribute__((address_space(3))) void*)l,
                                     16, 0, 0);
}

__device__ __forceinline__ void pbar() {
    __builtin_amdgcn_sched_barrier(0);
    asm volatile("" ::: "memory");
    __builtin_amdgcn_s_barrier();
    asm volatile("" ::: "memory");
    __builtin_amdgcn_sched_barrier(0);
}

__global__ __launch_bounds__(512, 2) void gemm256(const u16* __restrict__ A,
                                                  const u16* __restrict__ B,
                                                  float* __restrict__ C) {
    extern __shared__ __align__(16) u16 lds[];   // 4 * TILEU u16 = 128 KiB
    const int t = threadIdx.x;
    const int lane = t & 63;
    const int wid = t >> 6;
    const int wm = wid >> 2;   // 0..1
    const int wn = wid & 3;    // 0..3

    // block mapping: same-bm (shared A panel) blocks land on one XCD under
    // either bid%8 or bid/64 XCD assignment. 512 blocks, bijective.
    const int d = blockIdx.x;
    const int bm = (d & 7) | ((d >> 6) << 3);   // 0..63
    const int bn = (d >> 3) & 7;                // 0..7

    // fragment-read addressing (u16 units); chunk = (ks*4 + lane>>4) ^ (row&7)
    const int l15 = lane & 15;
    const int kq = lane >> 4;          // 0..3
    const int x7 = lane & 7;           // == row&7 for all frag rows (row = base16 + l15)
    const int c0 = (kq ^ x7) << 3;           // ks=0 chunk offset
    const int c1 = ((kq | 4) ^ x7) << 3;     // ks=1 chunk offset
    const int arow = (wm << 7) + l15;
    const int brow = (wn << 6) + l15;

    // staging: thread t, q=0..3 covers chunk c=q*512+t; row=c>>3, pos=c&7;
    // LDS slot (row,pos) receives global chunk pos^(row&7)  (source pre-swizzle)
    const int srow = t >> 3;                       // 0..63; q adds 64
    const int gch = ((t & 7) ^ (srow & 7)) << 3;
    const u16* Ag = A + (size_t)(bm * 256 + srow) * DDIM + gch;
    const u16* Bg = B + (size_t)(bn * 256 + srow) * DDIM + gch;

    floatx4 acc[8][4];
#pragma unroll
    for (int i = 0; i < 8; ++i)
#pragma unroll
        for (int j = 0; j < 4; ++j)
#pragma unroll
            for (int e = 0; e < 4; ++e) acc[i][j][e] = 0.f;

    bf16x8 a[4][2], b0v[2][2], b1v[2][2];

#define STAGE(gb, ldsoff, ko)                                                  \
    _Pragma("unroll") for (int q = 0; q < 4; ++q)                              \
        gl_lds16((gb) + (size_t)(q * 64) * DDIM + (ko),                        \
                 lds + (ldsoff) + q * 4096 + t * 8);

#define LDA(mh)                                                                \
    _Pragma("unroll") for (int fm = 0; fm < 4; ++fm) {                         \
        const u16* p = Ab + (arow + (mh) * 64 + fm * 16) * GBK;                \
        a[fm][0] = *(const bf16x8*)(p + c0);                                   \
        a[fm][1] = *(const bf16x8*)(p + c1);                                   \
    }

#define LDB(dst, nh)                                                           \
    _Pragma("unroll") for (int fn = 0; fn < 2; ++fn) {                         \
        const u16* p = Bb + (brow + (nh) * 32 + fn * 16) * GBK;                \
        dst[fn][0] = *(const bf16x8*)(p + c0);                                 \
        dst[fn][1] = *(const bf16x8*)(p + c1);                                 \
    }

#define MMA(mh, bsrc, nh)                                                      \
    __builtin_amdgcn_s_setprio(1);                                             \
    _Pragma("unroll") for (int fm = 0; fm < 4; ++fm)                           \
        _Pragma("unroll") for (int fn = 0; fn < 2; ++fn)                       \
            _Pragma("unroll") for (int ks = 0; ks < 2; ++ks)                   \
                acc[(mh) * 4 + fm][(nh) * 2 + fn] =                            \
                    __builtin_amdgcn_mfma_f32_16x16x32_bf16(                   \
                        a[fm][ks], bsrc[fn][ks],                               \
                        acc[(mh) * 4 + fm][(nh) * 2 + fn], 0, 0, 0);           \
    __builtin_amdgcn_s_setprio(0);

    // prologue: kt=0 -> buf0, kt=1 -> buf1; wait for kt=0 only (counted)
    STAGE(Ag, 0, 0);
    STAGE(Bg, TILEU, 0);
    STAGE(Ag, 2 * TILEU, GBK);
    STAGE(Bg, 3 * TILEU, GBK);
    __builtin_amdgcn_sched_barrier(0);
    asm volatile("s_waitcnt vmcnt(8)");
    pbar();

    for (int kt = 0; kt < GNT; ++kt) {
        const int boff = (kt & 1) * (2 * TILEU);
        const u16* Ab = lds + boff;
        const u16* Bb = lds + boff + TILEU;

        // P1: read A-half0 (8) + B-half0 (4)
        LDA(0);
        LDB(b0v, 0);
        pbar();
        MMA(0, b0v, 0);
        pbar();
        // P2: read B-half1 (4)
        LDB(b1v, 1);
        pbar();
        MMA(0, b1v, 1);
        pbar();
        // P3: read A-half1 (8); B tile fully consumed after P2 -> stage next B here
        LDA(1);
        if (kt + 2 < GNT) { STAGE(Bg, boff + TILEU, (kt + 2) * GBK); }
        pbar();
        MMA(1, b0v, 0);
        pbar();
        // P4: A tile fully consumed after P3 -> stage next A here
        if (kt + 2 < GNT) { STAGE(Ag, boff, (kt + 2) * GBK); }
        pbar();
        MMA(1, b1v, 1);
        __builtin_amdgcn_sched_barrier(0);
        if (kt < GNT - 2) {
            asm volatile("s_waitcnt vmcnt(8)");   // keep kt+2's 8 loads in flight
        } else {
            asm volatile("s_waitcnt vmcnt(0)");   // epilogue drain
        }
        pbar();
    }

#undef STAGE
#undef LDA
#undef LDB
#undef MMA

    // C/D layout 16x16x32 (m89/m91): col = lane&15, row = (lane>>4)*4 + reg
    float* Cb = C + (size_t)(bm * 256 + (wm << 7) + (lane >> 4) * 4) * DDIM
                  + bn * 256 + (wn << 6) + l15;
#pragma unroll
    for (int fm = 0; fm < 8; ++fm)
#pragma unroll
        for (int fn = 0; fn < 4; ++fn)
#pragma unroll
            for (int r = 0; r < 4; ++r)
                Cb[(size_t)(fm * 16 + r) * DDIM + fn * 16] = acc[fm][fn][r];
}

extern "C" void kernel_launch(void* const* d_in, const int* in_sizes, int n_in,
                              void* d_out, int out_size, void* d_ws, size_t ws_size,
                              hipStream_t stream) {
    const float* X  = (const float*)d_in[0];  // (4,4096,2048)
    const float* W  = (const float*)d_in[1];  // (2048,2048)
    const float* G  = (const float*)d_in[2];  // gamma
    const float* Bt = (const float*)d_in[3];  // beta
    float* out = (float*)d_out;

    char* ws = (char*)d_ws;
    u16*   xq   = (u16*)ws;                                       // 67,108,864 B
    float* bufA = (float*)(ws + (size_t)67108864);                // 16,777,216 B
    float* bufB = (float*)(ws + (size_t)67108864 + 16777216);     // 16,777,216 B
    float* partial = bufB;        // 1024 floats, transient (consumed by transpose<true>)
    u16*   w3      = (u16*)bufB;  // final bf16 weights, reuses bufB

    // w_scale partials
    absmean_part<<<1024, 256, 0, stream>>>((const float4*)W, partial);
    // w3 = H * ternary(W) * H, laid out [N=o][K=d] in bf16:
    transpose_k<true><<<dim3(32, 32), 256, 0, stream>>>(W, bufA, partial);     // bufA[d][o] = t^T
    fwht_rows<false><<<2048, 256, 0, stream>>>(bufA, (void*)bufB);             // bufB[d][o] = (H t)^T
    transpose_k<false><<<dim3(32, 32), 256, 0, stream>>>(bufB, bufA, nullptr); // bufA[o][d] = H t
    fwht_rows<true><<<2048, 256, 0, stream>>>(bufA, (void*)w3);                // w3[o][d] = H t H (bf16)
    // activations
    ln_quant<<<MROWS, 256, 0, stream>>>(X, G, Bt, xq);
    // GEMM (256x256 tile, 8-phase counted-vmcnt pipeline, 128 KiB dynamic LDS)
    hipFuncSetAttribute(reinterpret_cast<const void*>(gemm256),
                        hipFuncAttributeMaxDynamicSharedMemorySize, 131072);
    gemm256<<<dim3(512), 512, 131072, stream>>>(xq, w3, out);
}

// Round 2
// 376.986 us; speedup vs baseline: 1.0950x; 1.0563x over previous
//
#include <hip/hip_runtime.h>

typedef unsigned short u16;
typedef __attribute__((ext_vector_type(8))) __bf16 bf16x8;
typedef __attribute__((ext_vector_type(4))) float floatx4;

#define DDIM 2048
#define MROWS 16384   // 4*4096

__device__ __forceinline__ u16 f2bf(float f) {
    unsigned int u = __builtin_bit_cast(unsigned int, f);
    u = (u + 0x7fffu + ((u >> 16) & 1u)) >> 16;   // RNE
    return (u16)u;
}

__device__ __forceinline__ float wave_sum(float v) {
#pragma unroll
    for (int o = 32; o > 0; o >>= 1) v += __shfl_down(v, o, 64);
    return v;
}
__device__ __forceinline__ float wave_max(float v) {
#pragma unroll
    for (int o = 32; o > 0; o >>= 1) v = fmaxf(v, __shfl_down(v, o, 64));
    return v;
}

// ---------------- partial sums of |W| ----------------
__global__ __launch_bounds__(256) void absmean_part(const float4* __restrict__ W4,
                                                    float* __restrict__ partial) {
    float s = 0.f;
    for (int i = blockIdx.x * 256 + threadIdx.x; i < (DDIM * DDIM / 4); i += 1024 * 256) {
        float4 v = W4[i];
        s += fabsf(v.x) + fabsf(v.y) + fabsf(v.z) + fabsf(v.w);
    }
    s = wave_sum(s);
    __shared__ float red[4];
    if ((threadIdx.x & 63) == 0) red[threadIdx.x >> 6] = s;
    __syncthreads();
    if (threadIdx.x == 0) partial[blockIdx.x] = red[0] + red[1] + red[2] + red[3];
}

// ---------------- transpose (optionally fused w_scale finalize + ternary quantize) ----
template <bool QUANT>
__global__ __launch_bounds__(256) void transpose_k(const float* __restrict__ in,
                                                   float* __restrict__ out,
                                                   const float* __restrict__ partial) {
    __shared__ float tile[64][65];
    const int t = threadIdx.x;
    float wsc = 0.f, half_t = 0.f;
    if (QUANT) {
        __shared__ float wred[4];
        float s = partial[t] + partial[t + 256] + partial[t + 512] + partial[t + 768];
        s = wave_sum(s);
        if ((t & 63) == 0) wred[t >> 6] = s;
        __syncthreads();
        float m = (wred[0] + wred[1] + wred[2] + wred[3]) * (1.0f / (float)(DDIM * DDIM));
        wsc = fmaxf(m, 1e-6f);
        half_t = 0.5f * wsc;
        __syncthreads();
    }
    const int tx = t & 63;
    const int ty = t >> 6;
    const int r0 = blockIdx.y * 64;
    const int c0 = blockIdx.x * 64;
#pragma unroll
    for (int i = 0; i < 16; ++i) {
        int r = ty + i * 4;
        float w = in[(size_t)(r0 + r) * DDIM + c0 + tx];
        if (QUANT) w = (w > half_t ? wsc : 0.f) + (w < -half_t ? -wsc : 0.f);
        tile[r][tx] = w;
    }
    __syncthreads();
#pragma unroll
    for (int i = 0; i < 16; ++i) {
        int r = ty + i * 4;
        out[(size_t)(c0 + r) * DDIM + r0 + tx] = tile[tx][r];
    }
}

// ---------------- row FWHT (length 2048) -------------------------------------
template <bool BF16OUT>
__global__ __launch_bounds__(256) void fwht_rows(const float* __restrict__ in,
                                                 void* __restrict__ out) {
    __shared__ float s0[DDIM];
    __shared__ float s1[DDIM];
    const int row = blockIdx.x;
    const int t = threadIdx.x;
    const int lane = t & 63;
    const float4* rp = (const float4*)(in + (size_t)row * DDIM);
    float4 a = rp[t], b = rp[t + 256];
    float v[8] = {a.x, a.y, a.z, a.w, b.x, b.y, b.z, b.w};

#pragma unroll
    for (int h = 1; h <= 4; h <<= 1)
#pragma unroll
        for (int j = 0; j < 8; ++j)
            if (!(j & h)) { float x = v[j], y = v[j | h]; v[j] = x + y; v[j | h] = x - y; }

#pragma unroll
    for (int m = 1; m <= 32; m <<= 1)
#pragma unroll
        for (int j = 0; j < 8; ++j) {
            float p = __shfl_xor(v[j], m, 64);
            v[j] = (lane & m) ? (p - v[j]) : (p + v[j]);
        }

    ((float4*)s0)[2 * t] = make_float4(v[0], v[1], v[2], v[3]);
    ((float4*)s0)[2 * t + 1] = make_float4(v[4], v[5], v[6], v[7]);
    __syncthreads();
    {
        int p1 = t ^ 64;
        float4 pa = ((const float4*)s0)[2 * p1], pb = ((const float4*)s0)[2 * p1 + 1];
        float pv[8] = {pa.x, pa.y, pa.z, pa.w, pb.x, pb.y, pb.z, pb.w};
#pragma unroll
        for (int j = 0; j < 8; ++j) v[j] = (t & 64) ? (pv[j] - v[j]) : (pv[j] + v[j]);
    }
    ((float4*)s1)[2 * t] = make_float4(v[0], v[1], v[2], v[3]);
    ((float4*)s1)[2 * t + 1] = make_float4(v[4], v[5], v[6], v[7]);
    __syncthreads();
    {
        int p2 = t ^ 128;
        float4 pa = ((const float4*)s1)[2 * p2], pb = ((const float4*)s1)[2 * p2 + 1];
        float pv[8] = {pa.x, pa.y, pa.z, pa.w, pb.x, pb.y, pb.z, pb.w};
#pragma unroll
        for (int j = 0; j < 8; ++j) v[j] = (t & 128) ? (pv[j] - v[j]) : (pv[j] + v[j]);
    }

    if (BF16OUT) {
        u16* op = (u16*)out + (size_t)row * DDIM;
        uint2 o0, o1;
        o0.x = (unsigned)f2bf(v[0]) | ((unsigned)f2bf(v[1]) << 16);
        o0.y = (unsigned)f2bf(v[2]) | ((unsigned)f2bf(v[3]) << 16);
        o1.x = (unsigned)f2bf(v[4]) | ((unsigned)f2bf(v[5]) << 16);
        o1.y = (unsigned)f2bf(v[6]) | ((unsigned)f2bf(v[7]) << 16);
        ((uint2*)op)[t] = o0;
        ((uint2*)op)[t + 256] = o1;
    } else {
        float* op = (float*)out + (size_t)row * DDIM;
        ((float4*)op)[t] = make_float4(v[0], v[1], v[2], v[3]);
        ((float4*)op)[t + 256] = make_float4(v[4], v[5], v[6], v[7]);
    }
}

// ---------------- fused LayerNorm + int4 fake-quant -> bf16 ----------------
__global__ __launch_bounds__(256) void ln_quant(const float* __restrict__ X,
                                                const float* __restrict__ G,
                                                const float* __restrict__ Bt,
                                                u16* __restrict__ XQ) {
    const int row = blockIdx.x;
    const int t = threadIdx.x;
    const float4* rp = (const float4*)(X + (size_t)row * DDIM);
    float4 v0 = rp[t], v1 = rp[t + 256];
    float v[8] = {v0.x, v0.y, v0.z, v0.w, v1.x, v1.y, v1.z, v1.w};

    __shared__ float redA[4], redB[4], redC[4];
    const int wv = t >> 6, ln = t & 63;

    float s = 0.f, s2 = 0.f;
#pragma unroll
    for (int j = 0; j < 8; ++j) { s += v[j]; s2 += v[j] * v[j]; }
#pragma unroll
    for (int o = 32; o > 0; o >>= 1) {
        s += __shfl_down(s, o, 64);
        s2 += __shfl_down(s2, o, 64);
    }
    if (ln == 0) { redA[wv] = s; redB[wv] = s2; }
    __syncthreads();
    const float mu = (redA[0] + redA[1] + redA[2] + redA[3]) * (1.f / (float)DDIM);
    const float ex2 = (redB[0] + redB[1] + redB[2] + redB[3]) * (1.f / (float)DDIM);
    const float var = ex2 - mu * mu;
    const float rstd = rsqrtf(var + 1e-5f);

    const float4* gp = (const float4*)G;
    const float4* bp = (const float4*)Bt;
    float4 g0 = gp[t], g1 = gp[t + 256];
    float4 b0 = bp[t], b1 = bp[t + 256];
    float gg[8] = {g0.x, g0.y, g0.z, g0.w, g1.x, g1.y, g1.z, g1.w};
    float bb[8] = {b0.x, b0.y, b0.z, b0.w, b1.x, b1.y, b1.z, b1.w};

    float y[8];
    float am = 0.f;
#pragma unroll
    for (int j = 0; j < 8; ++j) {
        y[j] = (v[j] - mu) * rstd * gg[j] + bb[j];
        am = fmaxf(am, fabsf(y[j]));
    }
    float w = wave_max(am);
    if (ln == 0) redC[wv] = w;
    __syncthreads();
    const float scale = fmaxf(fmaxf(fmaxf(redC[0], redC[1]), fmaxf(redC[2], redC[3])), 1e-6f);

    const float r7 = 7.f / scale, s7 = scale / 7.f;
    unsigned int q[4];
#pragma unroll
    for (int j = 0; j < 8; j += 2) {
        float qa = fminf(fmaxf(rintf(y[j] * r7), -7.f), 7.f);
        float qb = fminf(fmaxf(rintf(y[j + 1] * r7), -7.f), 7.f);
        q[j >> 1] = (unsigned)f2bf(qa * s7) | ((unsigned)f2bf(qb * s7) << 16);
    }
    uint2 o0, o1;
    o0.x = q[0]; o0.y = q[1]; o1.x = q[2]; o1.y = q[3];
    uint2* orow = (uint2*)(XQ + (size_t)row * DDIM);
    orow[t] = o0;
    orow[t + 256] = o1;
}

// ---------------- GEMM: 256x256 tile, 8-phase, distributed staging ----------------
// C[16384][2048] = A[16384][2048] * B[2048(N)][2048(K)]^T, bf16 in / f32 out.
// 512 thr = 8 waves (2M x 4N); per-wave 128x64 output as 8x4 16x16x32 frags.
// Iteration = 2 K-tiles (even->buf0, odd->buf1), 8 phases, ONE barrier per phase.
// Stage schedule (2 gl_lds16/unit, region staged >=1 phase + barrier after last read):
//   ph2: A-q0,q2(kt+2)  ph3: B-q0,q1(kt+2)  ph4: B-q2,q3 + A-q1,q3(kt+2)
//   ph6: A-q0,q2(kt+3)  ph7: B-q0,q1(kt+3)  ph8: B-q2,q3 + A-q1,q3(kt+3)
// vmcnt(8) ONLY at ph4 (validates buf1/kt+1) and ph8 (validates buf0/kt+2);
// issue->wait distance = 4 phases (~2000cy >= HBM latency) -> zero steady stall.
#define GBK 64
#define GNT (DDIM / GBK)      // 32 K-tiles
#define NITER (GNT / 2)       // 16 iterations
#define TILEU (256 * GBK)     // 16384 u16 per staged tile

__device__ __forceinline__ void gl_lds16(const u16* g, u16* l) {
    __builtin_amdgcn_global_load_lds((const __attribute__((address_space(1))) void*)g,
                                     (__attribute__((address_space(3))) void*)l,
                                     16, 0, 0);
}

#define PBAR do {                                                              \
    __builtin_amdgcn_sched_barrier(0);                                         \
    asm volatile("" ::: "memory");                                             \
    __builtin_amdgcn_s_barrier();                                              \
    asm volatile("" ::: "memory");                                             \
    __builtin_amdgcn_sched_barrier(0);                                         \
} while (0)

#define PWAIT8 do {                                                            \
    __builtin_amdgcn_sched_barrier(0);                                         \
    asm volatile("s_waitcnt vmcnt(8)" ::: "memory");                           \
    __builtin_amdgcn_s_barrier();                                              \
    asm volatile("" ::: "memory");                                             \
    __builtin_amdgcn_sched_barrier(0);                                         \
} while (0)

#define PWAIT0 do {                                                            \
    __builtin_amdgcn_sched_barrier(0);                                         \
    asm volatile("s_waitcnt vmcnt(0)" ::: "memory");                           \
    __builtin_amdgcn_s_barrier();                                              \
    asm volatile("" ::: "memory");                                             \
    __builtin_amdgcn_sched_barrier(0);                                         \
} while (0)

__global__ __launch_bounds__(512, 2) void gemm256(const u16* __restrict__ A,
                                                  const u16* __restrict__ B,
                                                  float* __restrict__ C) {
    extern __shared__ __align__(16) u16 lds[];   // 4 * TILEU u16 = 128 KiB
    const int t = threadIdx.x;
    const int lane = t & 63;
    const int wid = t >> 6;
    const int wm = wid >> 2;   // 0..1
    const int wn = wid & 3;    // 0..3

    // block mapping: 8 consecutive d share bm (A panel) on one XCD; bijective.
    const int d = blockIdx.x;
    const int bm = (d & 7) | ((d >> 6) << 3);   // 0..63
    const int bn = (d >> 3) & 7;                // 0..7

    // fragment-read addressing (u16 units); chunk = (ks*4 + lane>>4) ^ (row&7)
    const int l15 = lane & 15;
    const int kq = lane >> 4;          // 0..3
    const int x7 = lane & 7;           // == row&7 (frag rows = 16*base + l15)
    const int c0 = (kq ^ x7) << 3;           // ks=0 chunk offset
    const int c1 = ((kq | 4) ^ x7) << 3;     // ks=1 chunk offset
    const int arow = (wm << 7) + l15;
    const int brow = (wn << 6) + l15;

    // staging: thread t covers chunk c = q*512 + t; row = c>>3, pos = c&7;
    // LDS slot (row,pos) receives global chunk pos^(row&7)  (source pre-swizzle)
    const int srow = t >> 3;                       // 0..63; q adds 64
    const int gch = ((t & 7) ^ (srow & 7)) << 3;
    const u16* Ag = A + (size_t)(bm * 256 + srow) * DDIM + gch;
    const u16* Bg = B + (size_t)(bn * 256 + srow) * DDIM + gch;
    u16* const AL0 = lds + t * 8;                  // + q*4096
    u16* const BL0 = lds + TILEU + t * 8;
    u16* const AL1 = lds + 2 * TILEU + t * 8;
    u16* const BL1 = lds + 3 * TILEU + t * 8;
    const u16* const Ab0 = lds;
    const u16* const Bb0 = lds + TILEU;
    const u16* const Ab1 = lds + 2 * TILEU;
    const u16* const Bb1 = lds + 3 * TILEU;

    floatx4 acc[8][4];
#pragma unroll
    for (int i = 0; i < 8; ++i)
#pragma unroll
        for (int j = 0; j < 4; ++j)
#pragma unroll
            for (int e = 0; e < 4; ++e) acc[i][j][e] = 0.f;

    bf16x8 a[4][2], b0v[2][2], b1v[2][2];

#define STGA(dst, q, ko) gl_lds16(Ag + (size_t)((q) * 64) * DDIM + (ko), (dst) + (q) * 4096)
#define STGB(dst, q, ko) gl_lds16(Bg + (size_t)((q) * 64) * DDIM + (ko), (dst) + (q) * 4096)

#define LDA(Ab, mh)                                                            \
    _Pragma("unroll") for (int fm = 0; fm < 4; ++fm) {                         \
        const u16* p = (Ab) + (arow + (mh) * 64 + fm * 16) * GBK;              \
        a[fm][0] = *(const bf16x8*)(p + c0);                                   \
        a[fm][1] = *(const bf16x8*)(p + c1);                                   \
    }

#define LDB(dst, Bb, nh)                                                       \
    _Pragma("unroll") for (int fn = 0; fn < 2; ++fn) {                         \
        const u16* p = (Bb) + (brow + (nh) * 32 + fn * 16) * GBK;              \
        dst[fn][0] = *(const bf16x8*)(p + c0);                                 \
        dst[fn][1] = *(const bf16x8*)(p + c1);                                 \
    }

#define MMA(mh, bsrc, nh)                                                      \
    __builtin_amdgcn_s_setprio(1);                                             \
    _Pragma("unroll") for (int fm = 0; fm < 4; ++fm)                           \
        _Pragma("unroll") for (int fn = 0; fn < 2; ++fn)                       \
            _Pragma("unroll") for (int ks = 0; ks < 2; ++ks)                   \
                acc[(mh) * 4 + fm][(nh) * 2 + fn] =                            \
                    __builtin_amdgcn_mfma_f32_16x16x32_bf16(                   \
                        a[fm][ks], bsrc[fn][ks],                               \
                        acc[(mh) * 4 + fm][(nh) * 2 + fn], 0, 0, 0);           \
    __builtin_amdgcn_s_setprio(0);

    // prologue: tile0 -> buf0, tile1 -> buf1; wait tile0 only (8 newest in flight)
#pragma unroll
    for (int q = 0; q < 4; ++q) STGA(AL0, q, 0);
#pragma unroll
    for (int q = 0; q < 4; ++q) STGB(BL0, q, 0);
#pragma unroll
    for (int q = 0; q < 4; ++q) STGA(AL1, q, GBK);
#pragma unroll
    for (int q = 0; q < 4; ++q) STGB(BL1, q, GBK);
    PWAIT8;

    for (int it = 0; it < NITER; ++it) {
        const int kp0 = (it * 2 + 2) * GBK;   // K offset of tile 2it+2 (buf0)
        const int kp1 = kp0 + GBK;            // tile 2it+3 (buf1)
        const bool pf = (it < NITER - 1);

        // ---- K-tile 2it (buf0) ----
        // ph1: read A0,B0
        LDA(Ab0, 0);
        LDB(b0v, Bb0, 0);
        PBAR;
        MMA(0, b0v, 0);
        // ph2: read B1; stage A-q0,q2 (kt+2)
        LDB(b1v, Bb0, 1);
        if (pf) { STGA(AL0, 0, kp0); STGA(AL0, 2, kp0); }
        PBAR;
        MMA(0, b1v, 1);
        // ph3: read A1; stage B-q0,q1 (kt+2)
        LDA(Ab0, 1);
        if (pf) { STGB(BL0, 0, kp0); STGB(BL0, 1, kp0); }
        PBAR;
        MMA(1, b0v, 0);
        // ph4: stage B-q2,q3 + A-q1,q3 (kt+2); wait validates buf1 (kt+1)
        if (pf) { STGB(BL0, 2, kp0); STGB(BL0, 3, kp0); STGA(AL0, 1, kp0); STGA(AL0, 3, kp0); }
        if (pf) { PWAIT8; } else { PWAIT0; }
        MMA(1, b1v, 1);

        // ---- K-tile 2it+1 (buf1) ----
        // ph5: read A0,B0
        LDA(Ab1, 0);
        LDB(b0v, Bb1, 0);
        PBAR;
        MMA(0, b0v, 0);
        // ph6: read B1; stage A-q0,q2 (kt+3)
        LDB(b1v, Bb1, 1);
        if (pf) { STGA(AL1, 0, kp1); STGA(AL1, 2, kp1); }
        PBAR;
        MMA(0, b1v, 1);
        // ph7: read A1; stage B-q0,q1 (kt+3)
        LDA(Ab1, 1);
        if (pf) { STGB(BL1, 0, kp1); STGB(BL1, 1, kp1); }
        PBAR;
        MMA(1, b0v, 0);
        // ph8: stage B-q2,q3 + A-q1,q3 (kt+3); wait validates buf0 (kt+2)
        if (pf) { STGB(BL1, 2, kp1); STGB(BL1, 3, kp1); STGA(AL1, 1, kp1); STGA(AL1, 3, kp1); }
        if (pf) { PWAIT8; } else { PWAIT0; }
        MMA(1, b1v, 1);
    }

#undef STGA
#undef STGB
#undef LDA
#undef LDB
#undef MMA

    // C/D layout 16x16x32 (m89/m91): col = lane&15, row = (lane>>4)*4 + reg
    float* Cb = C + (size_t)(bm * 256 + (wm << 7) + (lane >> 4) * 4) * DDIM
                  + bn * 256 + (wn << 6) + l15;
#pragma unroll
    for (int fm = 0; fm < 8; ++fm)
#pragma unroll
        for (int fn = 0; fn < 4; ++fn)
#pragma unroll
            for (int r = 0; r < 4; ++r)
                Cb[(size_t)(fm * 16 + r) * DDIM + fn * 16] = acc[fm][fn][r];
}

extern "C" void kernel_launch(void* const* d_in, const int* in_sizes, int n_in,
                              void* d_out, int out_size, void* d_ws, size_t ws_size,
                              hipStream_t stream) {
    const float* X  = (const float*)d_in[0];  // (4,4096,2048)
    const float* W  = (const float*)d_in[1];  // (2048,2048)
    const float* G  = (const float*)d_in[2];  // gamma
    const float* Bt = (const float*)d_in[3];  // beta
    float* out = (float*)d_out;

    char* ws = (char*)d_ws;
    u16*   xq   = (u16*)ws;                                       // 67,108,864 B
    float* bufA = (float*)(ws + (size_t)67108864);                // 16,777,216 B
    float* bufB = (float*)(ws + (size_t)67108864 + 16777216);     // 16,777,216 B
    float* partial = bufB;        // 1024 floats, transient (consumed by transpose<true>)
    u16*   w3      = (u16*)bufB;  // final bf16 weights, reuses bufB

    // w_scale partials
    absmean_part<<<1024, 256, 0, stream>>>((const float4*)W, partial);
    // w3 = H * ternary(W) * H, laid out [N=o][K=d] in bf16:
    transpose_k<true><<<dim3(32, 32), 256, 0, stream>>>(W, bufA, partial);     // bufA[d][o] = t^T
    fwht_rows<false><<<2048, 256, 0, stream>>>(bufA, (void*)bufB);             // bufB[d][o] = (H t)^T
    transpose_k<false><<<dim3(32, 32), 256, 0, stream>>>(bufB, bufA, nullptr); // bufA[o][d] = H t
    fwht_rows<true><<<2048, 256, 0, stream>>>(bufA, (void*)w3);                // w3[o][d] = H t H (bf16)
    // activations
    ln_quant<<<MROWS, 256, 0, stream>>>(X, G, Bt, xq);
    // GEMM (256x256 tile, 8-phase distributed-stage pipeline, 128 KiB dynamic LDS)
    hipFuncSetAttribute(reinterpret_cast<const void*>(gemm256),
                        hipFuncAttributeMaxDynamicSharedMemorySize, 131072);
    gemm256<<<dim3(512), 512, 131072, stream>>>(xq, w3, out);
}